// Round 1
// baseline (535.373 us; speedup 1.0000x reference)
//
#include <hip/hip_runtime.h>

#define N_NODES_C  100000
#define N_GRAPHS_C 1000
#define NPG_C      100
#define N_EDGES_C  3200000
#define KTOP_C     30

// ---------------- workspace layout (floats) ----------------
// A   : [0, 10,000,000)            dense per-graph normalized adjacency, 1000 x 100 x 100
// deg : [10,000,000, 10,100,000)
// dis : [10,100,000, 10,200,000)

__global__ void deg_kernel(const int* __restrict__ src, const int* __restrict__ dst,
                           float* __restrict__ deg) {
    int e = blockIdx.x * blockDim.x + threadIdx.x;
    if (e >= N_EDGES_C) return;
    int s = src[e], d = dst[e];
    if (s != d) atomicAdd(&deg[d], 1.0f);
}

__global__ void dis_diag_kernel(const float* __restrict__ deg, float* __restrict__ dis,
                                float* __restrict__ A) {
    int i = blockIdx.x * blockDim.x + threadIdx.x;
    if (i >= N_NODES_C) return;
    float v = rsqrtf(deg[i] + 1.0f);
    dis[i] = v;
    int g = i / NPG_C, li = i - g * NPG_C;
    A[g * NPG_C * NPG_C + li * NPG_C + li] = v * v;   // self-loop coeff 1/deg
}

__global__ void edgeA_kernel(const int* __restrict__ src, const int* __restrict__ dst,
                             const float* __restrict__ dis, float* __restrict__ A) {
    int e = blockIdx.x * blockDim.x + threadIdx.x;
    if (e >= N_EDGES_C) return;
    int s = src[e], d = dst[e];
    if (s == d) return;
    int g = s / NPG_C;
    atomicAdd(&A[g * NPG_C * NPG_C + (d - g * NPG_C) * NPG_C + (s - g * NPG_C)],
              dis[s] * dis[d]);
}

// ---------------- main per-graph kernel ----------------
// LDS layout (floats):
//  sA   [10000]     adjacency
//  sB   [12800]     X (100x128) during layer 1; afterwards aliased as:
//                    sX1 = sB+0 (3200), sX2 = sB+3200, sX3 = sB+6400, sX4 = sB+9600 (100)
//  sT   [3200]      H@W staging (100x32)
//  s5   [480]  sP [240]  s6 [352]  sO1 [128]  sFc [512]  sZ [16]  sOrd [32 ints]
#define SMEM_FLOATS 27760

extern "C" __global__ __launch_bounds__(512)
void dgcnn_kernel(const float* __restrict__ x, const float* __restrict__ A,
                  const float* __restrict__ W1, const float* __restrict__ b1,
                  const float* __restrict__ W2, const float* __restrict__ b2,
                  const float* __restrict__ W3, const float* __restrict__ b3,
                  const float* __restrict__ W4, const float* __restrict__ b4,
                  const float* __restrict__ w5, const float* __restrict__ b5,
                  const float* __restrict__ w6, const float* __restrict__ b6,
                  const float* __restrict__ fw1, const float* __restrict__ fb1,
                  const float* __restrict__ fw2, const float* __restrict__ fb2,
                  float* __restrict__ out)
{
    extern __shared__ float sm[];
    float* sA  = sm;              // 10000
    float* sB  = sm + 10000;      // 12800
    float* sX  = sB;
    float* sX1 = sB;              // alias: valid after sX dead
    float* sX2 = sB + 3200;
    float* sX3 = sB + 6400;
    float* sX4 = sB + 9600;       // 100
    float* sT  = sm + 22800;      // 3200
    float* s5  = sm + 26000;      // 480
    float* sP  = sm + 26480;      // 240
    float* s6  = sm + 26720;      // 352
    float* sO1 = sm + 27072;      // 128
    float* sFc = sm + 27200;      // 512
    float* sZ  = sm + 27712;      // 16
    int*  sOrd = (int*)(sm + 27728); // 32

    const int tid = threadIdx.x;
    const int g   = blockIdx.x;
    const int f   = tid & 31;
    const int i0  = tid >> 5;     // 0..15

    // ---- load A (100x100) and X (100x128) ----
    for (int idx = tid; idx < 10000; idx += 512) sA[idx] = A[g * 10000 + idx];
    {
        const float4* xg = (const float4*)(x + (size_t)g * NPG_C * 128);
        float4* sx4p = (float4*)sX;
        for (int idx = tid; idx < 3200; idx += 512) sx4p[idx] = xg[idx];
    }
    __syncthreads();

    // ---- layer 1: sT = X @ W1 (128 -> 32) ----
    {
        float acc[7] = {0,0,0,0,0,0,0};
        for (int c4 = 0; c4 < 128; c4 += 4) {
            float w0 = W1[(c4+0)*32+f], w1 = W1[(c4+1)*32+f];
            float w2 = W1[(c4+2)*32+f], w3 = W1[(c4+3)*32+f];
            #pragma unroll
            for (int r = 0; r < 7; ++r) {
                int i = i0 + (r << 4);
                if (i < 100) {
                    const float4 xv = *(const float4*)&sX[i*128 + c4];
                    acc[r] = fmaf(xv.x,w0, fmaf(xv.y,w1, fmaf(xv.z,w2, fmaf(xv.w,w3, acc[r]))));
                }
            }
        }
        __syncthreads();   // everyone done reading sX before sT write? sT disjoint; barrier after stores below
        #pragma unroll
        for (int r = 0; r < 7; ++r) { int i = i0 + (r << 4); if (i < 100) sT[i*32+f] = acc[r]; }
    }
    __syncthreads();

    // ---- agg macro: O = tanh(A @ sT + b), O is 100x32 ----
#define AGG32(OUT, BIAS)                                                            \
    {                                                                               \
        float acc[7] = {0,0,0,0,0,0,0};                                             \
        for (int k4 = 0; k4 < 100; k4 += 4) {                                       \
            float t0 = sT[(k4+0)*32+f], t1 = sT[(k4+1)*32+f];                       \
            float t2 = sT[(k4+2)*32+f], t3 = sT[(k4+3)*32+f];                       \
            _Pragma("unroll")                                                       \
            for (int r = 0; r < 7; ++r) {                                           \
                int i = i0 + (r << 4);                                              \
                if (i < 100) {                                                      \
                    const float4 av = *(const float4*)&sA[i*100 + k4];              \
                    acc[r] = fmaf(av.x,t0, fmaf(av.y,t1, fmaf(av.z,t2, fmaf(av.w,t3, acc[r])))); \
                }                                                                   \
            }                                                                       \
        }                                                                           \
        float bf = BIAS[f];                                                         \
        _Pragma("unroll")                                                           \
        for (int r = 0; r < 7; ++r) { int i = i0 + (r << 4); if (i < 100) OUT[i*32+f] = tanhf(acc[r] + bf); } \
    }

    // ---- XW macro for 32->32: sT = IN @ W ----
#define XW32(IN, W)                                                                 \
    {                                                                               \
        float acc[7] = {0,0,0,0,0,0,0};                                             \
        for (int c4 = 0; c4 < 32; c4 += 4) {                                        \
            float w0 = W[(c4+0)*32+f], w1 = W[(c4+1)*32+f];                         \
            float w2 = W[(c4+2)*32+f], w3 = W[(c4+3)*32+f];                         \
            _Pragma("unroll")                                                       \
            for (int r = 0; r < 7; ++r) {                                           \
                int i = i0 + (r << 4);                                              \
                if (i < 100) {                                                      \
                    const float4 xv = *(const float4*)&IN[i*32 + c4];               \
                    acc[r] = fmaf(xv.x,w0, fmaf(xv.y,w1, fmaf(xv.z,w2, fmaf(xv.w,w3, acc[r])))); \
                }                                                                   \
            }                                                                       \
        }                                                                           \
        _Pragma("unroll")                                                           \
        for (int r = 0; r < 7; ++r) { int i = i0 + (r << 4); if (i < 100) sT[i*32+f] = acc[r]; } \
    }

    AGG32(sX1, b1);          // x1 = tanh(A @ (X W1) + b1)   (overwrites dead sX)
    __syncthreads();
    XW32(sX1, W2);
    __syncthreads();
    AGG32(sX2, b2);
    __syncthreads();
    XW32(sX2, W3);
    __syncthreads();
    AGG32(sX3, b3);
    __syncthreads();

    // ---- layer 4 (32 -> 1) ----
    if (tid < 100) {
        float acc = 0.f;
        for (int c4 = 0; c4 < 32; c4 += 4) {
            const float4 xv = *(const float4*)&sX3[tid*32 + c4];
            acc = fmaf(xv.x, W4[c4+0], fmaf(xv.y, W4[c4+1], fmaf(xv.z, W4[c4+2], fmaf(xv.w, W4[c4+3], acc))));
        }
        sT[tid] = acc;
    }
    __syncthreads();
    if (tid < 100) {
        float acc = 0.f;
        for (int k4 = 0; k4 < 100; k4 += 4) {
            const float4 av = *(const float4*)&sA[tid*100 + k4];
            acc = fmaf(av.x, sT[k4+0], fmaf(av.y, sT[k4+1], fmaf(av.z, sT[k4+2], fmaf(av.w, sT[k4+3], acc))));
        }
        sX4[tid] = tanhf(acc + b4[0]);
    }
    __syncthreads();

    // ---- SortAggregation: stable rank by (value desc, index asc), keep top-30 ----
    if (tid < 100) {
        float vi = sX4[tid];
        int r = 0;
        for (int j = 0; j < 100; ++j) {
            float vj = sX4[j];
            r += (vj > vi) || (vj == vi && j < tid);
        }
        if (r < KTOP_C) sOrd[r] = tid;
    }
    __syncthreads();

    // ---- conv5 (97 -> 16, per pooled node) + ReLU ----
    if (tid < 480) {
        int co = tid / 30, l = tid - co * 30;
        int n = sOrd[l];
        const float* wr = w5 + co * 97;
        float acc = b5[co];
        for (int c4 = 0; c4 < 32; c4 += 4) {
            const float4 a1 = *(const float4*)&sX1[n*32 + c4];
            acc = fmaf(a1.x, wr[c4+0], fmaf(a1.y, wr[c4+1], fmaf(a1.z, wr[c4+2], fmaf(a1.w, wr[c4+3], acc))));
        }
        for (int c4 = 0; c4 < 32; c4 += 4) {
            const float4 a2 = *(const float4*)&sX2[n*32 + c4];
            acc = fmaf(a2.x, wr[32+c4+0], fmaf(a2.y, wr[32+c4+1], fmaf(a2.z, wr[32+c4+2], fmaf(a2.w, wr[32+c4+3], acc))));
        }
        for (int c4 = 0; c4 < 32; c4 += 4) {
            const float4 a3 = *(const float4*)&sX3[n*32 + c4];
            acc = fmaf(a3.x, wr[64+c4+0], fmaf(a3.y, wr[64+c4+1], fmaf(a3.z, wr[64+c4+2], fmaf(a3.w, wr[64+c4+3], acc))));
        }
        acc = fmaf(sX4[n], wr[96], acc);
        s5[co * 30 + l] = fmaxf(acc, 0.f);
    }
    __syncthreads();

    // ---- maxpool(2,2): [16][30] -> [16][15] ----
    if (tid < 240) {
        int co = tid / 15, j = tid - co * 15;
        sP[co * 15 + j] = fmaxf(s5[co * 30 + 2*j], s5[co * 30 + 2*j + 1]);
    }
    __syncthreads();

    // ---- conv6 (16 -> 32, k=5) + ReLU: [32][11] ----
    if (tid < 352) {
        int co = tid / 11, l = tid - co * 11;
        float acc = b6[co];
        for (int ci = 0; ci < 16; ++ci) {
            const float* wr = w6 + (co * 16 + ci) * 5;
            const float* pr = sP + ci * 15 + l;
            acc = fmaf(wr[0], pr[0], fmaf(wr[1], pr[1], fmaf(wr[2], pr[2],
                  fmaf(wr[3], pr[3], fmaf(wr[4], pr[4], acc)))));
        }
        s6[co * 11 + l] = fmaxf(acc, 0.f);
    }
    __syncthreads();

    // ---- fc1 (352 -> 128) + ReLU, split dot over 4 partitions ----
    {
        int j = tid & 127, part = tid >> 7;  // 0..3
        int ibeg = part * 88, iend = ibeg + 88;
        float acc = (part == 0) ? fb1[j] : 0.f;
        for (int i = ibeg; i < iend; ++i)
            acc = fmaf(s6[i], fw1[i * 128 + j], acc);
        sFc[part * 128 + j] = acc;
    }
    __syncthreads();
    if (tid < 128) {
        float v = sFc[tid] + sFc[128 + tid] + sFc[256 + tid] + sFc[384 + tid];
        sO1[tid] = fmaxf(v, 0.f);
    }
    __syncthreads();

    // ---- fc2 (128 -> 10) ----
    if (tid < 10) {
        float acc = fb2[tid];
        for (int k = 0; k < 128; ++k)
            acc = fmaf(sO1[k], fw2[k * 10 + tid], acc);
        sZ[tid] = acc;
    }
    __syncthreads();

    // ---- log_softmax ----
    if (tid < 10) {
        float m = sZ[0];
        for (int c = 1; c < 10; ++c) m = fmaxf(m, sZ[c]);
        float se = 0.f;
        for (int c = 0; c < 10; ++c) se += expf(sZ[c] - m);
        out[g * 10 + tid] = sZ[tid] - m - logf(se);
    }
}

extern "C" void kernel_launch(void* const* d_in, const int* in_sizes, int n_in,
                              void* d_out, int out_size, void* d_ws, size_t ws_size,
                              hipStream_t stream) {
    const float* x   = (const float*)d_in[0];
    const int*   ei  = (const int*)d_in[1];
    const int*   src = ei;
    const int*   dst = ei + N_EDGES_C;
    // d_in[2] = batch (unused: graphs are contiguous 100-node blocks)
    const float* W1 = (const float*)d_in[3];  const float* b1 = (const float*)d_in[4];
    const float* W2 = (const float*)d_in[5];  const float* b2 = (const float*)d_in[6];
    const float* W3 = (const float*)d_in[7];  const float* b3 = (const float*)d_in[8];
    const float* W4 = (const float*)d_in[9];  const float* b4 = (const float*)d_in[10];
    const float* w5 = (const float*)d_in[11]; const float* b5 = (const float*)d_in[12];
    const float* w6 = (const float*)d_in[13]; const float* b6 = (const float*)d_in[14];
    const float* fw1 = (const float*)d_in[15]; const float* fb1 = (const float*)d_in[16];
    const float* fw2 = (const float*)d_in[17]; const float* fb2 = (const float*)d_in[18];
    float* out = (float*)d_out;

    float* A   = (float*)d_ws;                 // 10,000,000 floats
    float* deg = A + 10000000;                 // 100,000
    float* dis = deg + 100000;                 // 100,000

    // zero A + deg (dis is fully overwritten)
    hipMemsetAsync(d_ws, 0, (size_t)(10000000 + 100000) * sizeof(float), stream);

    deg_kernel<<<(N_EDGES_C + 255) / 256, 256, 0, stream>>>(src, dst, deg);
    dis_diag_kernel<<<(N_NODES_C + 255) / 256, 256, 0, stream>>>(deg, dis, A);
    edgeA_kernel<<<(N_EDGES_C + 255) / 256, 256, 0, stream>>>(src, dst, dis, A);

    size_t smem = (size_t)SMEM_FLOATS * sizeof(float);  // ~111 KB
    hipFuncSetAttribute((const void*)dgcnn_kernel,
                        hipFuncAttributeMaxDynamicSharedMemorySize, (int)smem);
    dgcnn_kernel<<<N_GRAPHS_C, 512, smem, stream>>>(
        x, A, W1, b1, W2, b2, W3, b3, W4, b4,
        w5, b5, w6, b6, fw1, fb1, fw2, fb2, out);
}

// Round 2
// 442.371 us; speedup vs baseline: 1.2102x; 1.2102x over previous
//
#include <hip/hip_runtime.h>

#define N_NODES_C  100000
#define N_GRAPHS_C 1000
#define NPG_C      100
#define N_EDGES_C  3200000
#define KTOP_C     30

// ---------------- workspace layout (floats) ----------------
// cnt : [0, 10,000,000)  raw edge-count matrix, 1000 x 100(dst) x 100(src)

__global__ void edge_cnt_kernel(const int* __restrict__ src, const int* __restrict__ dst,
                                float* __restrict__ cnt) {
    int e = blockIdx.x * blockDim.x + threadIdx.x;
    if (e >= N_EDGES_C) return;
    int s = src[e], d = dst[e];
    if (s == d) return;
    int g = s / NPG_C;
    atomicAdd(&cnt[g * NPG_C * NPG_C + (d - g * NPG_C) * NPG_C + (s - g * NPG_C)], 1.0f);
}

// ---------------- main per-graph kernel ----------------
// LDS (floats): sX1[3200] sX2[3200] sX3[3200] sX4[100] dis[100] sT[3200]
// Tail buffers alias into sT (dead after layer 4).
#define SMEM_FLOATS 13000

extern "C" __global__ __launch_bounds__(512)
void dgcnn_kernel(const float* __restrict__ x, const float* __restrict__ cnt,
                  const float* __restrict__ W1, const float* __restrict__ b1,
                  const float* __restrict__ W2, const float* __restrict__ b2,
                  const float* __restrict__ W3, const float* __restrict__ b3,
                  const float* __restrict__ W4, const float* __restrict__ b4,
                  const float* __restrict__ w5, const float* __restrict__ b5,
                  const float* __restrict__ w6, const float* __restrict__ b6,
                  const float* __restrict__ fw1, const float* __restrict__ fb1,
                  const float* __restrict__ fw2, const float* __restrict__ fb2,
                  float* __restrict__ out)
{
    extern __shared__ float sm[];
    float* sX1 = sm;              // 3200
    float* sX2 = sm + 3200;       // 3200
    float* sX3 = sm + 6400;       // 3200
    float* sX4 = sm + 9600;       // 100
    float* dis = sm + 9700;       // 100
    float* sT  = sm + 9800;       // 3200
    // tail aliases (sT dead after layer 4):
    int*   sOrd = (int*)(sT);     // 32
    float* s5   = sT + 32;        // 480
    float* sP   = sT + 512;       // 240
    float* s6   = sT + 752;       // 352
    float* sO1  = sT + 1104;      // 128
    float* sFc  = sT + 1232;      // 512
    float* sZ   = sT + 1744;      // 16

    const int tid = threadIdx.x;
    const int g   = blockIdx.x;
    const int f   = tid & 31;
    const int i0  = tid >> 5;     // 0..15

    const float* cg = cnt + (size_t)g * 10000;
    const float* xg = x + (size_t)g * NPG_C * 128;

    // ---- deg = row-sum of cnt; dis = rsqrt(deg+1) ----
    if (tid < 500) {
        int row = tid / 5, seg = tid - row * 5;
        const float4* p = (const float4*)(cg + row * 100 + seg * 20);
        float s = 0.f;
        #pragma unroll
        for (int k = 0; k < 5; ++k) { float4 v = p[k]; s += v.x + v.y + v.z + v.w; }
        sT[tid] = s;
    }
    __syncthreads();
    if (tid < 100) {
        float d = sT[tid*5] + sT[tid*5+1] + sT[tid*5+2] + sT[tid*5+3] + sT[tid*5+4];
        dis[tid] = rsqrtf(d + 1.0f);
    }
    __syncthreads();

    // ---- layer 1: sT = (X @ W1) * dis  (X streamed from global) ----
    {
        float acc[7] = {0,0,0,0,0,0,0};
        for (int c4 = 0; c4 < 128; c4 += 4) {
            float w0 = W1[(c4+0)*32+f], w1 = W1[(c4+1)*32+f];
            float w2 = W1[(c4+2)*32+f], w3 = W1[(c4+3)*32+f];
            #pragma unroll
            for (int r = 0; r < 7; ++r) {
                int i = i0 + (r << 4);
                if (i < 100) {
                    const float4 xv = *(const float4*)&xg[i*128 + c4];
                    acc[r] = fmaf(xv.x,w0, fmaf(xv.y,w1, fmaf(xv.z,w2, fmaf(xv.w,w3, acc[r]))));
                }
            }
        }
        #pragma unroll
        for (int r = 0; r < 7; ++r) { int i = i0 + (r << 4); if (i < 100) sT[i*32+f] = acc[r]*dis[i]; }
    }
    __syncthreads();

    // ---- AGG: OUT = tanh(dis[i]*(cnt_row_i . sT + sT[i]) + b) ----
#define AGG32(OUT, BIAS)                                                            \
    {                                                                               \
        float acc[7] = {0,0,0,0,0,0,0};                                             \
        for (int k4 = 0; k4 < 100; k4 += 4) {                                       \
            float t0 = sT[(k4+0)*32+f], t1 = sT[(k4+1)*32+f];                       \
            float t2 = sT[(k4+2)*32+f], t3 = sT[(k4+3)*32+f];                       \
            _Pragma("unroll")                                                       \
            for (int r = 0; r < 7; ++r) {                                           \
                int i = i0 + (r << 4);                                              \
                if (i < 100) {                                                      \
                    const float4 av = *(const float4*)&cg[i*100 + k4];              \
                    acc[r] = fmaf(av.x,t0, fmaf(av.y,t1, fmaf(av.z,t2, fmaf(av.w,t3, acc[r])))); \
                }                                                                   \
            }                                                                       \
        }                                                                           \
        float bf = BIAS[f];                                                         \
        _Pragma("unroll")                                                           \
        for (int r = 0; r < 7; ++r) {                                               \
            int i = i0 + (r << 4);                                                  \
            if (i < 100) OUT[i*32+f] = tanhf(dis[i]*(acc[r] + sT[i*32+f]) + bf);    \
        }                                                                           \
    }

    // ---- XW32: sT = (IN @ W) * dis ----
#define XW32(IN, W)                                                                 \
    {                                                                               \
        float acc[7] = {0,0,0,0,0,0,0};                                             \
        for (int c4 = 0; c4 < 32; c4 += 4) {                                        \
            float w0 = W[(c4+0)*32+f], w1 = W[(c4+1)*32+f];                         \
            float w2 = W[(c4+2)*32+f], w3 = W[(c4+3)*32+f];                         \
            _Pragma("unroll")                                                       \
            for (int r = 0; r < 7; ++r) {                                           \
                int i = i0 + (r << 4);                                              \
                if (i < 100) {                                                      \
                    const float4 xv = *(const float4*)&IN[i*32 + c4];               \
                    acc[r] = fmaf(xv.x,w0, fmaf(xv.y,w1, fmaf(xv.z,w2, fmaf(xv.w,w3, acc[r])))); \
                }                                                                   \
            }                                                                       \
        }                                                                           \
        __syncthreads();                                                            \
        _Pragma("unroll")                                                           \
        for (int r = 0; r < 7; ++r) { int i = i0 + (r << 4); if (i < 100) sT[i*32+f] = acc[r]*dis[i]; } \
    }

    AGG32(sX1, b1);
    __syncthreads();
    XW32(sX1, W2);          // has internal sync before overwriting sT
    __syncthreads();
    AGG32(sX2, b2);
    __syncthreads();
    XW32(sX2, W3);
    __syncthreads();
    AGG32(sX3, b3);
    __syncthreads();

    // ---- layer 4 (32 -> 1) ----
    if (tid < 100) {
        float acc = 0.f;
        for (int c4 = 0; c4 < 32; c4 += 4) {
            const float4 xv = *(const float4*)&sX3[tid*32 + c4];
            acc = fmaf(xv.x, W4[c4+0], fmaf(xv.y, W4[c4+1], fmaf(xv.z, W4[c4+2], fmaf(xv.w, W4[c4+3], acc))));
        }
        sT[tid] = acc * dis[tid];
    }
    __syncthreads();
    if (tid < 100) {
        float acc = 0.f;
        for (int k4 = 0; k4 < 100; k4 += 4) {
            const float4 av = *(const float4*)&cg[tid*100 + k4];
            acc = fmaf(av.x, sT[k4+0], fmaf(av.y, sT[k4+1], fmaf(av.z, sT[k4+2], fmaf(av.w, sT[k4+3], acc))));
        }
        sX4[tid] = tanhf(dis[tid]*(acc + sT[tid]) + b4[0]);
    }
    __syncthreads();

    // ---- SortAggregation: stable rank (value desc, index asc), top-30 ----
    if (tid < 100) {
        float vi = sX4[tid];
        int r = 0;
        for (int j = 0; j < 100; ++j) {
            float vj = sX4[j];
            r += (vj > vi) || (vj == vi && j < tid);
        }
        if (r < KTOP_C) sOrd[r] = tid;
    }
    __syncthreads();

    // ---- conv5 (97 -> 16) + ReLU. 16 lanes share a node row (broadcast). ----
    if (tid < 480) {
        int l = tid >> 4, co = tid & 15;   // l: pooled slot 0..29, co: out channel
        int n = sOrd[l];
        const float* wr = w5 + co * 97;
        float acc = b5[co];
        for (int c4 = 0; c4 < 32; c4 += 4) {
            const float4 a1 = *(const float4*)&sX1[n*32 + c4];
            acc = fmaf(a1.x, wr[c4+0], fmaf(a1.y, wr[c4+1], fmaf(a1.z, wr[c4+2], fmaf(a1.w, wr[c4+3], acc))));
        }
        for (int c4 = 0; c4 < 32; c4 += 4) {
            const float4 a2 = *(const float4*)&sX2[n*32 + c4];
            acc = fmaf(a2.x, wr[32+c4+0], fmaf(a2.y, wr[32+c4+1], fmaf(a2.z, wr[32+c4+2], fmaf(a2.w, wr[32+c4+3], acc))));
        }
        for (int c4 = 0; c4 < 32; c4 += 4) {
            const float4 a3 = *(const float4*)&sX3[n*32 + c4];
            acc = fmaf(a3.x, wr[64+c4+0], fmaf(a3.y, wr[64+c4+1], fmaf(a3.z, wr[64+c4+2], fmaf(a3.w, wr[64+c4+3], acc))));
        }
        acc = fmaf(sX4[n], wr[96], acc);
        s5[co * 30 + l] = fmaxf(acc, 0.f);
    }
    __syncthreads();

    // ---- maxpool(2,2): [16][30] -> [16][15] ----
    if (tid < 240) {
        int co = tid / 15, j = tid - co * 15;
        sP[co * 15 + j] = fmaxf(s5[co * 30 + 2*j], s5[co * 30 + 2*j + 1]);
    }
    __syncthreads();

    // ---- conv6 (16 -> 32, k=5) + ReLU: [32][11] ----
    if (tid < 352) {
        int co = tid / 11, l = tid - co * 11;
        float acc = b6[co];
        for (int ci = 0; ci < 16; ++ci) {
            const float* wr = w6 + (co * 16 + ci) * 5;
            const float* pr = sP + ci * 15 + l;
            acc = fmaf(wr[0], pr[0], fmaf(wr[1], pr[1], fmaf(wr[2], pr[2],
                  fmaf(wr[3], pr[3], fmaf(wr[4], pr[4], acc)))));
        }
        s6[co * 11 + l] = fmaxf(acc, 0.f);
    }
    __syncthreads();

    // ---- fc1 (352 -> 128) + ReLU ----
    {
        int j = tid & 127, part = tid >> 7;  // 0..3
        int ibeg = part * 88, iend = ibeg + 88;
        float acc = (part == 0) ? fb1[j] : 0.f;
        for (int i = ibeg; i < iend; ++i)
            acc = fmaf(s6[i], fw1[i * 128 + j], acc);
        sFc[part * 128 + j] = acc;
    }
    __syncthreads();
    if (tid < 128) {
        float v = sFc[tid] + sFc[128 + tid] + sFc[256 + tid] + sFc[384 + tid];
        sO1[tid] = fmaxf(v, 0.f);
    }
    __syncthreads();

    // ---- fc2 (128 -> 10) + log_softmax ----
    if (tid < 10) {
        float acc = fb2[tid];
        for (int k = 0; k < 128; ++k)
            acc = fmaf(sO1[k], fw2[k * 10 + tid], acc);
        sZ[tid] = acc;
    }
    __syncthreads();
    if (tid < 10) {
        float m = sZ[0];
        for (int c = 1; c < 10; ++c) m = fmaxf(m, sZ[c]);
        float se = 0.f;
        for (int c = 0; c < 10; ++c) se += expf(sZ[c] - m);
        out[g * 10 + tid] = sZ[tid] - m - logf(se);
    }
}

extern "C" void kernel_launch(void* const* d_in, const int* in_sizes, int n_in,
                              void* d_out, int out_size, void* d_ws, size_t ws_size,
                              hipStream_t stream) {
    const float* x   = (const float*)d_in[0];
    const int*   ei  = (const int*)d_in[1];
    const int*   src = ei;
    const int*   dst = ei + N_EDGES_C;
    const float* W1 = (const float*)d_in[3];  const float* b1 = (const float*)d_in[4];
    const float* W2 = (const float*)d_in[5];  const float* b2 = (const float*)d_in[6];
    const float* W3 = (const float*)d_in[7];  const float* b3 = (const float*)d_in[8];
    const float* W4 = (const float*)d_in[9];  const float* b4 = (const float*)d_in[10];
    const float* w5 = (const float*)d_in[11]; const float* b5 = (const float*)d_in[12];
    const float* w6 = (const float*)d_in[13]; const float* b6 = (const float*)d_in[14];
    const float* fw1 = (const float*)d_in[15]; const float* fb1 = (const float*)d_in[16];
    const float* fw2 = (const float*)d_in[17]; const float* fb2 = (const float*)d_in[18];
    float* out = (float*)d_out;

    float* cnt = (float*)d_ws;   // 10,000,000 floats

    hipMemsetAsync(d_ws, 0, (size_t)10000000 * sizeof(float), stream);

    edge_cnt_kernel<<<(N_EDGES_C + 255) / 256, 256, 0, stream>>>(src, dst, cnt);

    size_t smem = (size_t)SMEM_FLOATS * sizeof(float);  // 52 KB
    hipFuncSetAttribute((const void*)dgcnn_kernel,
                        hipFuncAttributeMaxDynamicSharedMemorySize, (int)smem);
    dgcnn_kernel<<<N_GRAPHS_C, 512, smem, stream>>>(
        x, cnt, W1, b1, W2, b2, W3, b3, W4, b4,
        w5, b5, w6, b6, fw1, fb1, fw2, fb2, out);
}

// Round 4
// 215.047 us; speedup vs baseline: 2.4896x; 2.0571x over previous
//
#include <hip/hip_runtime.h>

#define N_NODES_C  100000
#define N_GRAPHS_C 1000
#define NPG_C      100
#define N_EDGES_C  3200000
#define KTOP_C     30
#define CAP        4096      // per-graph edge-slot capacity (mean 3200, sigma ~57)

// ---------------- workspace layout (bytes) ----------------
// [0, 4096)            : gcur  int[1024]  (per-graph cursors; memset to 0)
// [4096, 4096+8.2MB)   : slots u16[1000*4096]  packed edges (d<<7 | s)

__global__ __launch_bounds__(1024)
void bucket_kernel(const int* __restrict__ src, const int* __restrict__ dst,
                   int* __restrict__ gcur, unsigned short* __restrict__ slots) {
    __shared__ int hist[N_GRAPHS_C];
    const int tid = threadIdx.x;
    const int base = blockIdx.x * 8192;
    for (int i = tid; i < N_GRAPHS_C; i += 1024) hist[i] = 0;
    __syncthreads();

    int g[8]; unsigned short pk[8]; bool v[8];
    #pragma unroll
    for (int k = 0; k < 8; ++k) {
        int e = base + tid + k * 1024;
        v[k] = false;
        if (e < N_EDGES_C) {
            int s = src[e], d = dst[e];
            if (s != d) {
                int gg = s / NPG_C;           // src and dst share the graph
                g[k] = gg;
                pk[k] = (unsigned short)(((d - gg * NPG_C) << 7) | (s - gg * NPG_C));
                v[k] = true;
                atomicAdd(&hist[gg], 1);
            }
        }
    }
    __syncthreads();
    for (int i = tid; i < N_GRAPHS_C; i += 1024) {
        int c = hist[i];
        hist[i] = atomicAdd(&gcur[i], c);     // reserve [base, base+c) globally
    }
    __syncthreads();
    #pragma unroll
    for (int k = 0; k < 8; ++k) {
        if (v[k]) {
            int pos = atomicAdd(&hist[g[k]], 1);
            if (pos < CAP) slots[g[k] * CAP + pos] = pk[k];
        }
    }
}

// ---------------- main per-graph kernel ----------------
// LDS (floats): sA[10000] sT[3200] sH[3200] dis[100] t4[100] sX4[100]
//               sdeg(int)[100] srank(int)[100] sOrd(int)[32]
// pooled[30][100] aliases sT after layer 4; tail buffers alias sH.
#define SMEM_FLOATS 16932

extern "C" __global__ __launch_bounds__(512)
void dgcnn_kernel(const float* __restrict__ x,
                  const int* __restrict__ gcur, const unsigned short* __restrict__ slots,
                  const float* __restrict__ W1, const float* __restrict__ b1,
                  const float* __restrict__ W2, const float* __restrict__ b2,
                  const float* __restrict__ W3, const float* __restrict__ b3,
                  const float* __restrict__ W4, const float* __restrict__ b4,
                  const float* __restrict__ w5, const float* __restrict__ b5,
                  const float* __restrict__ w6, const float* __restrict__ b6,
                  const float* __restrict__ fw1, const float* __restrict__ fb1,
                  const float* __restrict__ fw2, const float* __restrict__ fb2,
                  float* __restrict__ out)
{
    extern __shared__ float sm[];
    float* sA   = sm;                 // 10000
    float* sT   = sm + 10000;         // 3200
    float* sH   = sm + 13200;         // 3200
    float* dis  = sm + 16400;         // 100
    float* t4   = sm + 16500;         // 100
    float* sX4  = sm + 16600;         // 100
    int*   sdeg = (int*)(sm + 16700); // 100
    int*   srank= (int*)(sm + 16800); // 100
    int*   sOrd = (int*)(sm + 16900); // 32
    float* pooled = sT;               // [30][100], valid after layer 4
    float* s5   = sH;                 // 480
    float* sP   = sH + 480;           // 240
    float* s6   = sH + 720;           // 352
    float* sO1  = sH + 1072;          // 128
    float* sFc  = sH + 1200;          // 512
    float* sZ   = sH + 1712;          // 16

    const int tid = threadIdx.x;
    const int g   = blockIdx.x;
    const int f   = tid & 31;
    const int i0  = tid >> 5;         // 0..15

    const float* xg = x + (size_t)g * NPG_C * 128;

    // ---- zero A/deg, load this graph's edge list into regs ----
    {
        float4 z4 = {0.f, 0.f, 0.f, 0.f};
        float4* a4 = (float4*)sA;
        for (int idx = tid; idx < 2500; idx += 512) a4[idx] = z4;
        if (tid < 100) sdeg[tid] = 0;
    }
    int ec = gcur[g]; if (ec > CAP) ec = CAP;
    unsigned short ek[8]; int ne = 0;
    for (int k = tid; k < ec; k += 512) ek[ne++] = slots[g * CAP + k];
    __syncthreads();

    for (int j = 0; j < ne; ++j) atomicAdd(&sdeg[ek[j] >> 7], 1);
    __syncthreads();
    if (tid < 100) {
        float dv = rsqrtf((float)sdeg[tid] + 1.0f);
        dis[tid] = dv;
        sA[tid * 100 + tid] = dv * dv;          // self-loop coefficient
    }
    __syncthreads();
    for (int j = 0; j < ne; ++j) {
        int d = ek[j] >> 7, s = ek[j] & 127;
        atomicAdd(&sA[d * 100 + s], dis[s] * dis[d]);
    }
    __syncthreads();

    // ---- layer 1: sT = X @ W1 (128 -> 32), X streamed from global ----
    {
        float acc[7] = {0,0,0,0,0,0,0};
        for (int c4 = 0; c4 < 128; c4 += 4) {
            float w0 = W1[(c4+0)*32+f], w1 = W1[(c4+1)*32+f];
            float w2 = W1[(c4+2)*32+f], w3 = W1[(c4+3)*32+f];
            #pragma unroll
            for (int r = 0; r < 7; ++r) {
                int i = i0 + (r << 4);
                if (i < 100) {
                    const float4 xv = *(const float4*)&xg[i*128 + c4];
                    acc[r] = fmaf(xv.x,w0, fmaf(xv.y,w1, fmaf(xv.z,w2, fmaf(xv.w,w3, acc[r]))));
                }
            }
        }
        #pragma unroll
        for (int r = 0; r < 7; ++r) { int i = i0 + (r << 4); if (i < 100) sT[i*32+f] = acc[r]; }
    }
    __syncthreads();

    // ---- AGG: XR[r] = tanh(A_row_i . sT + b); optionally mirror to sH ----
#define AGG_REG(XR, BIAS, WRITE_SH)                                                 \
    {                                                                               \
        float acc[7] = {0,0,0,0,0,0,0};                                             \
        for (int k4 = 0; k4 < 100; k4 += 4) {                                       \
            float t0 = sT[(k4+0)*32+f], t1 = sT[(k4+1)*32+f];                       \
            float t2 = sT[(k4+2)*32+f], t3 = sT[(k4+3)*32+f];                       \
            _Pragma("unroll")                                                       \
            for (int r = 0; r < 7; ++r) {                                           \
                int i = i0 + (r << 4);                                              \
                if (i < 100) {                                                      \
                    const float4 av = *(const float4*)&sA[i*100 + k4];              \
                    acc[r] = fmaf(av.x,t0, fmaf(av.y,t1, fmaf(av.z,t2, fmaf(av.w,t3, acc[r])))); \
                }                                                                   \
            }                                                                       \
        }                                                                           \
        float bf = BIAS[f];                                                         \
        _Pragma("unroll")                                                           \
        for (int r = 0; r < 7; ++r) {                                               \
            int i = i0 + (r << 4);                                                  \
            if (i < 100) {                                                          \
                float o = tanhf(acc[r] + bf);                                       \
                XR[r] = o;                                                          \
                if (WRITE_SH) sH[i*32+f] = o;                                       \
            }                                                                       \
        }                                                                           \
    }

    // ---- XW: sT = sH @ W (32 -> 32) ----
#define XW32(W)                                                                     \
    {                                                                               \
        float acc[7] = {0,0,0,0,0,0,0};                                             \
        for (int c4 = 0; c4 < 32; c4 += 4) {                                        \
            float w0 = W[(c4+0)*32+f], w1 = W[(c4+1)*32+f];                         \
            float w2 = W[(c4+2)*32+f], w3 = W[(c4+3)*32+f];                         \
            _Pragma("unroll")                                                       \
            for (int r = 0; r < 7; ++r) {                                           \
                int i = i0 + (r << 4);                                              \
                if (i < 100) {                                                      \
                    const float4 xv = *(const float4*)&sH[i*32 + c4];               \
                    acc[r] = fmaf(xv.x,w0, fmaf(xv.y,w1, fmaf(xv.z,w2, fmaf(xv.w,w3, acc[r])))); \
                }                                                                   \
            }                                                                       \
        }                                                                           \
        _Pragma("unroll")                                                           \
        for (int r = 0; r < 7; ++r) { int i = i0 + (r << 4); if (i < 100) sT[i*32+f] = acc[r]; } \
    }

    float xr1[7], xr2[7], xr3[7];
    AGG_REG(xr1, b1, 1);       // x1, mirrored to sH
    __syncthreads();
    XW32(W2);                  // reads sH, writes sT (disjoint)
    __syncthreads();
    AGG_REG(xr2, b2, 1);
    __syncthreads();
    XW32(W3);
    __syncthreads();
    AGG_REG(xr3, b3, 0);       // x3 lives only in registers

    // ---- layer 4 (32 -> 1): per-row dot via shfl reduce ----
    {
        float w4f = W4[f];
        #pragma unroll
        for (int r = 0; r < 7; ++r) {
            int i = i0 + (r << 4);
            float v = (i < 100) ? xr3[r] * w4f : 0.f;
            #pragma unroll
            for (int off = 16; off >= 1; off >>= 1) v += __shfl_xor(v, off, 32);
            if (f == 0 && i < 100) t4[i] = v;
        }
    }
    __syncthreads();
    if (tid < 100) {
        float acc = 0.f;
        for (int k4 = 0; k4 < 100; k4 += 4) {
            const float4 av = *(const float4*)&sA[tid*100 + k4];
            acc = fmaf(av.x, t4[k4+0], fmaf(av.y, t4[k4+1], fmaf(av.z, t4[k4+2], fmaf(av.w, t4[k4+3], acc))));
        }
        sX4[tid] = tanhf(acc + b4[0]);
    }
    __syncthreads();

    // ---- SortAggregation: stable rank (value desc, index asc), top-30 ----
    if (tid < 100) {
        float vi = sX4[tid];
        int r = 0;
        for (int j = 0; j < 100; ++j) {
            float vj = sX4[j];
            r += (vj > vi) || (vj == vi && j < tid);
        }
        srank[tid] = r;
        if (r < KTOP_C) sOrd[r] = tid;
    }
    __syncthreads();

    // ---- gather top-30 rows from registers into pooled[30][100] (stride 100) ----
    #pragma unroll
    for (int r = 0; r < 7; ++r) {
        int i = i0 + (r << 4);
        if (i < 100) {
            int rk = srank[i];
            if (rk < KTOP_C) {
                float* pr = pooled + rk * 100;
                pr[f]      = xr1[r];
                pr[32 + f] = xr2[r];
                pr[64 + f] = xr3[r];
                if (f == 0) pr[96] = sX4[i];
            }
        }
    }
    __syncthreads();

    // ---- conv5 (97 -> 16) + ReLU ----
    if (tid < 480) {
        int l = tid >> 4, co = tid & 15;
        const float* pr = pooled + l * 100;
        const float* wr = w5 + co * 97;
        float acc = b5[co];
        for (int c4 = 0; c4 < 96; c4 += 4) {
            const float4 pv = *(const float4*)&pr[c4];
            acc = fmaf(pv.x, wr[c4+0], fmaf(pv.y, wr[c4+1], fmaf(pv.z, wr[c4+2], fmaf(pv.w, wr[c4+3], acc))));
        }
        acc = fmaf(pr[96], wr[96], acc);
        s5[co * 30 + l] = fmaxf(acc, 0.f);
    }
    __syncthreads();

    // ---- maxpool(2,2): [16][30] -> [16][15] ----
    if (tid < 240) {
        int co = tid / 15, j = tid - co * 15;
        sP[co * 15 + j] = fmaxf(s5[co * 30 + 2*j], s5[co * 30 + 2*j + 1]);
    }
    __syncthreads();

    // ---- conv6 (16 -> 32, k=5) + ReLU: [32][11] ----
    if (tid < 352) {
        int co = tid / 11, l = tid - co * 11;
        float acc = b6[co];
        for (int ci = 0; ci < 16; ++ci) {
            const float* wr = w6 + (co * 16 + ci) * 5;
            const float* pr = sP + ci * 15 + l;
            acc = fmaf(wr[0], pr[0], fmaf(wr[1], pr[1], fmaf(wr[2], pr[2],
                  fmaf(wr[3], pr[3], fmaf(wr[4], pr[4], acc)))));
        }
        s6[co * 11 + l] = fmaxf(acc, 0.f);
    }
    __syncthreads();

    // ---- fc1 (352 -> 128) + ReLU ----
    {
        int j = tid & 127, part = tid >> 7;  // 0..3
        int ibeg = part * 88, iend = ibeg + 88;
        float acc = (part == 0) ? fb1[j] : 0.f;
        for (int i = ibeg; i < iend; ++i)
            acc = fmaf(s6[i], fw1[i * 128 + j], acc);
        sFc[part * 128 + j] = acc;
    }
    __syncthreads();
    if (tid < 128) {
        float v = sFc[tid] + sFc[128 + tid] + sFc[256 + tid] + sFc[384 + tid];
        sO1[tid] = fmaxf(v, 0.f);
    }
    __syncthreads();

    // ---- fc2 (128 -> 10) + log_softmax ----
    if (tid < 10) {
        float acc = fb2[tid];
        for (int k = 0; k < 128; ++k)
            acc = fmaf(sO1[k], fw2[k * 10 + tid], acc);
        sZ[tid] = acc;
    }
    __syncthreads();
    if (tid < 10) {
        float m = sZ[0];
        for (int c = 1; c < 10; ++c) m = fmaxf(m, sZ[c]);
        float se = 0.f;
        for (int c = 0; c < 10; ++c) se += expf(sZ[c] - m);
        out[g * 10 + tid] = sZ[tid] - m - logf(se);
    }
}

extern "C" void kernel_launch(void* const* d_in, const int* in_sizes, int n_in,
                              void* d_out, int out_size, void* d_ws, size_t ws_size,
                              hipStream_t stream) {
    const float* x   = (const float*)d_in[0];
    const int*   ei  = (const int*)d_in[1];
    const int*   src = ei;
    const int*   dst = ei + N_EDGES_C;
    const float* W1 = (const float*)d_in[3];  const float* b1 = (const float*)d_in[4];
    const float* W2 = (const float*)d_in[5];  const float* b2 = (const float*)d_in[6];
    const float* W3 = (const float*)d_in[7];  const float* b3 = (const float*)d_in[8];
    const float* W4 = (const float*)d_in[9];  const float* b4 = (const float*)d_in[10];
    const float* w5 = (const float*)d_in[11]; const float* b5 = (const float*)d_in[12];
    const float* w6 = (const float*)d_in[13]; const float* b6 = (const float*)d_in[14];
    const float* fw1 = (const float*)d_in[15]; const float* fb1 = (const float*)d_in[16];
    const float* fw2 = (const float*)d_in[17]; const float* fb2 = (const float*)d_in[18];
    float* out = (float*)d_out;

    int* gcur = (int*)d_ws;
    unsigned short* slots = (unsigned short*)((char*)d_ws + 4096);

    hipMemsetAsync(gcur, 0, 4096, stream);

    bucket_kernel<<<(N_EDGES_C + 8191) / 8192, 1024, 0, stream>>>(src, dst, gcur, slots);

    size_t smem = (size_t)SMEM_FLOATS * sizeof(float);  // ~66 KB -> 2 blocks/CU
    hipFuncSetAttribute((const void*)dgcnn_kernel,
                        hipFuncAttributeMaxDynamicSharedMemorySize, (int)smem);
    dgcnn_kernel<<<N_GRAPHS_C, 512, smem, stream>>>(
        x, gcur, slots, W1, b1, W2, b2, W3, b3, W4, b4,
        w5, b5, w6, b6, fw1, fb1, fw2, fb2, out);
}

// Round 6
// 203.823 us; speedup vs baseline: 2.6267x; 1.0551x over previous
//
#include <hip/hip_runtime.h>

#define N_GRAPHS_C 1000
#define NPG_C      100
#define N_EDGES_C  3200000
#define KTOP_C     30
#define CAP        4096      // per-graph edge-slot capacity (mean 3200, sigma ~57)

// ---------------- workspace layout (bytes) ----------------
// [0, 4096)            : gcur  int[1024]  (per-graph cursors; memset to 0)
// [4096, 4096+8.2MB)   : slots u16[1000*4096]  packed edges (d<<7 | s)

__global__ __launch_bounds__(1024)
void bucket_kernel(const int* __restrict__ src, const int* __restrict__ dst,
                   int* __restrict__ gcur, unsigned short* __restrict__ slots) {
    __shared__ int hist[N_GRAPHS_C];
    const int tid = threadIdx.x;
    const int base = blockIdx.x * 8192;
    for (int i = tid; i < N_GRAPHS_C; i += 1024) hist[i] = 0;
    __syncthreads();

    int g[8]; unsigned short pk[8]; bool v[8];
    #pragma unroll
    for (int k = 0; k < 8; ++k) {
        int e = base + tid + k * 1024;
        v[k] = false;
        if (e < N_EDGES_C) {
            int s = src[e], d = dst[e];
            if (s != d) {
                int gg = s / NPG_C;           // src and dst share the graph
                g[k] = gg;
                pk[k] = (unsigned short)(((d - gg * NPG_C) << 7) | (s - gg * NPG_C));
                v[k] = true;
                atomicAdd(&hist[gg], 1);
            }
        }
    }
    __syncthreads();
    for (int i = tid; i < N_GRAPHS_C; i += 1024) {
        int c = hist[i];
        hist[i] = atomicAdd(&gcur[i], c);     // reserve [base, base+c) globally
    }
    __syncthreads();
    #pragma unroll
    for (int k = 0; k < 8; ++k) {
        if (v[k]) {
            int pos = atomicAdd(&hist[g[k]], 1);
            if (pos < CAP) slots[g[k] * CAP + pos] = pk[k];
        }
    }
}

// ---------------- main per-graph kernel ----------------
// LDS (float offsets), total 13500 floats = 54,000 B -> 3 blocks/CU:
//  sA  f32[100][100]            : [0, 10000)      fp32 normalized adjacency (row stride 400B, f4-aligned)
//  buf f32[3200]                : [10000, 13200)  ping-pong: cnt(u8) -> T^t -> x rows -> T^t ... -> pooled
//  dis f32[100]                 : [13200, 13300)
//  t4  f32[100] (srank later)   : [13300, 13400)
//  sX4 f32[100]                 : [13400, 13500)
//  tail s5/sP/s6/sO1/sFc/sZ alias sA (dead after layer-4 dot)
#define SMEM_FLOATS 13500

extern "C" __global__ __launch_bounds__(512, 6)
void dgcnn_kernel(const float* __restrict__ x,
                  const int* __restrict__ gcur, const unsigned short* __restrict__ slots,
                  const float* __restrict__ W1, const float* __restrict__ b1,
                  const float* __restrict__ W2, const float* __restrict__ b2,
                  const float* __restrict__ W3, const float* __restrict__ b3,
                  const float* __restrict__ W4, const float* __restrict__ b4,
                  const float* __restrict__ w5, const float* __restrict__ b5,
                  const float* __restrict__ w6, const float* __restrict__ b6,
                  const float* __restrict__ fw1, const float* __restrict__ fb1,
                  const float* __restrict__ fw2, const float* __restrict__ fb2,
                  float* __restrict__ out)
{
    extern __shared__ float sm[];
    float* sA  = sm;                       // 10000
    float* buf = sm + 10000;               // 3200
    float* dis = sm + 13200;               // 100
    float* t4  = sm + 13300;               // 100
    float* sX4 = sm + 13400;               // 100
    unsigned*            cnt32 = (unsigned*)buf;             // 2500 words (prep only)
    const unsigned char* cnt8  = (const unsigned char*)buf;  // 10000 bytes
    int*   srank  = (int*)t4;              // aliases t4 (dead after layer-4 dot)
    float* pooled = buf;                   // [30][100] after GCN
    float* s5  = sA;                       // 480   (sA dead after layer-4 dot)
    float* sP  = sA + 480;                 // 240
    float* s6  = sA + 720;                 // 352
    float* sO1 = sA + 1072;                // 128
    float* sFc = sA + 1200;                // 512
    float* sZ  = sA + 1712;                // 16

    const int tid = threadIdx.x;
    const int g   = blockIdx.x;
    const int f   = tid & 31;
    const int i0  = tid >> 5;              // 0..15

    const float* xg = x + (size_t)g * NPG_C * 128;

    // ---- phase 1: zero counts ----
    for (int idx = tid; idx < 2500; idx += 512) cnt32[idx] = 0u;
    __syncthreads();

    // ---- phase 2: scatter u8 counts (packed u32 atomics) ----
    {
        int ec = gcur[g]; if (ec > CAP) ec = CAP;
        for (int k = tid; k < ec; k += 512) {
            unsigned e = slots[g * CAP + k];
            unsigned idx = (e >> 7) * 100 + (e & 127);
            atomicAdd(&cnt32[idx >> 2], 1u << ((idx & 3) * 8));
        }
    }
    __syncthreads();

    // ---- phase 3: dis = rsqrt(rowsum + 1) ----
    if (tid < 100) {
        const unsigned* rw = cnt32 + tid * 25;
        unsigned s = 0;
        #pragma unroll
        for (int k = 0; k < 25; ++k) {
            unsigned v = rw[k];
            s += (v & 0xffu) + ((v >> 8) & 0xffu) + ((v >> 16) & 0xffu) + (v >> 24);
        }
        dis[tid] = rsqrtf((float)s + 1.0f);
    }
    __syncthreads();

    // ---- phase 4: build fp32 A: A[d][k] = cnt*dis_k*dis_d (+dis_d^2 on diag) ----
    for (int w = tid; w < 10000; w += 512) {
        int d = w / 100, k = w - d * 100;
        float v = (float)cnt8[w] * dis[k] * dis[d];
        if (k == d) v += dis[d] * dis[d];
        sA[w] = v;
    }
    __syncthreads();   // cnt (in buf) dead from here; buf reused

    // ---- layer 1: T1 = X @ W1 (128 -> 32), written transposed buf[f][i] ----
    {
        float acc[7] = {0,0,0,0,0,0,0};
        for (int c4 = 0; c4 < 128; c4 += 4) {
            float w0 = W1[(c4+0)*32+f], w1 = W1[(c4+1)*32+f];
            float w2 = W1[(c4+2)*32+f], w3 = W1[(c4+3)*32+f];
            #pragma unroll
            for (int r = 0; r < 7; ++r) {
                int i = i0 + (r << 4);
                if (i < 100) {
                    const float4 xv = *(const float4*)&xg[i*128 + c4];
                    acc[r] = fmaf(xv.x,w0, fmaf(xv.y,w1, fmaf(xv.z,w2, fmaf(xv.w,w3, acc[r]))));
                }
            }
        }
        #pragma unroll
        for (int r = 0; r < 7; ++r) { int i = i0 + (r << 4); if (i < 100) buf[f*100 + i] = acc[r]; }
    }
    __syncthreads();

    // ---- AGG: XR[r] = tanh(A_row_i . T_col_f + b); A f32 b128, T^t f4 reads ----
#define AGG_REG(XR, BIAS)                                                           \
    {                                                                               \
        float acc[7] = {0,0,0,0,0,0,0};                                             \
        const float* tp = buf + f * 100;                                            \
        for (int k4 = 0; k4 < 100; k4 += 4) {                                       \
            const float4 tv = *(const float4*)&tp[k4];                              \
            _Pragma("unroll")                                                       \
            for (int r = 0; r < 7; ++r) {                                           \
                int i = i0 + (r << 4);                                              \
                if (i < 100) {                                                      \
                    const float4 av = *(const float4*)&sA[i*100 + k4];              \
                    acc[r] = fmaf(av.x,tv.x, fmaf(av.y,tv.y, fmaf(av.z,tv.z,        \
                             fmaf(av.w,tv.w, acc[r]))));                            \
                }                                                                   \
            }                                                                       \
        }                                                                           \
        float bf_ = BIAS[f];                                                        \
        _Pragma("unroll")                                                           \
        for (int r = 0; r < 7; ++r) {                                               \
            int i = i0 + (r << 4);                                                  \
            if (i < 100) XR[r] = tanhf(acc[r] + bf_);                               \
        }                                                                           \
    }

    // ---- store x rows (row-major) into buf ----
#define STORE_ROWS(XR)                                                              \
    {                                                                               \
        _Pragma("unroll")                                                           \
        for (int r = 0; r < 7; ++r) { int i = i0 + (r << 4); if (i < 100) buf[i*32 + f] = XR[r]; } \
    }

    // ---- XW: TT[r] = (buf_rows @ W)[i][f]  (broadcast f4 reads of buf rows) ----
#define XW32(TT, W)                                                                 \
    {                                                                               \
        _Pragma("unroll")                                                           \
        for (int r = 0; r < 7; ++r) TT[r] = 0.f;                                    \
        for (int c4 = 0; c4 < 32; c4 += 4) {                                        \
            float w0 = W[(c4+0)*32+f], w1 = W[(c4+1)*32+f];                         \
            float w2 = W[(c4+2)*32+f], w3 = W[(c4+3)*32+f];                         \
            _Pragma("unroll")                                                       \
            for (int r = 0; r < 7; ++r) {                                           \
                int i = i0 + (r << 4);                                              \
                if (i < 100) {                                                      \
                    const float4 xv = *(const float4*)&buf[i*32 + c4];              \
                    TT[r] = fmaf(xv.x,w0, fmaf(xv.y,w1, fmaf(xv.z,w2, fmaf(xv.w,w3, TT[r])))); \
                }                                                                   \
            }                                                                       \
        }                                                                           \
    }

    // ---- store T transposed into buf ----
#define STORE_TT(TT)                                                                \
    {                                                                               \
        _Pragma("unroll")                                                           \
        for (int r = 0; r < 7; ++r) { int i = i0 + (r << 4); if (i < 100) buf[f*100 + i] = TT[r]; } \
    }

    float xr1[7], xr2[7], xr3[7], tt[7];

    AGG_REG(xr1, b1);          // reads buf = T1^t
    __syncthreads();
    STORE_ROWS(xr1);           // buf = x1 rows
    __syncthreads();
    XW32(tt, W2);
    __syncthreads();
    STORE_TT(tt);              // buf = T2^t
    __syncthreads();
    AGG_REG(xr2, b2);
    __syncthreads();
    STORE_ROWS(xr2);
    __syncthreads();
    XW32(tt, W3);
    __syncthreads();
    STORE_TT(tt);              // buf = T3^t
    __syncthreads();
    AGG_REG(xr3, b3);          // x3 in registers only

    // ---- layer 4 (32 -> 1): row dot via half-wave shfl reduce ----
    {
        float w4f = W4[f];
        #pragma unroll
        for (int r = 0; r < 7; ++r) {
            int i = i0 + (r << 4);
            float v = (i < 100) ? xr3[r] * w4f : 0.f;
            #pragma unroll
            for (int off = 16; off >= 1; off >>= 1) v += __shfl_xor(v, off, 32);
            if (f == 0 && i < 100) t4[i] = v;
        }
    }
    __syncthreads();
    if (tid < 100) {
        float acc = 0.f;
        const float* ar = sA + tid * 100;
        for (int k4 = 0; k4 < 100; k4 += 4) {
            const float4 av = *(const float4*)&ar[k4];
            const float4 tv = *(const float4*)&t4[k4];
            acc = fmaf(av.x,tv.x, fmaf(av.y,tv.y, fmaf(av.z,tv.z, fmaf(av.w,tv.w, acc))));
        }
        sX4[tid] = tanhf(acc + b4[0]);
    }
    __syncthreads();

    // ---- SortAggregation: stable rank (value desc, index asc), top-30 ----
    if (tid < 100) {
        float vi = sX4[tid];
        int r = 0;
        for (int j = 0; j < 100; ++j) {
            float vj = sX4[j];
            r += (vj > vi) || (vj == vi && j < tid);
        }
        srank[tid] = r;        // overwrites dead t4
    }
    __syncthreads();

    // ---- gather top-30 rows into pooled[30][100] (aliases buf, dead) ----
    #pragma unroll
    for (int r = 0; r < 7; ++r) {
        int i = i0 + (r << 4);
        if (i < 100) {
            int rk = srank[i];
            if (rk < KTOP_C) {
                float* pr = pooled + rk * 100;
                pr[f]      = xr1[r];
                pr[32 + f] = xr2[r];
                pr[64 + f] = xr3[r];
                if (f == 0) pr[96] = sX4[i];
            }
        }
    }
    __syncthreads();

    // ---- conv5 (97 -> 16) + ReLU ----
    if (tid < 480) {
        int l = tid >> 4, co = tid & 15;
        const float* pr = pooled + l * 100;
        const float* wr = w5 + co * 97;
        float acc = b5[co];
        for (int c4 = 0; c4 < 96; c4 += 4) {
            const float4 pv = *(const float4*)&pr[c4];
            acc = fmaf(pv.x, wr[c4+0], fmaf(pv.y, wr[c4+1], fmaf(pv.z, wr[c4+2], fmaf(pv.w, wr[c4+3], acc))));
        }
        acc = fmaf(pr[96], wr[96], acc);
        s5[co * 30 + l] = fmaxf(acc, 0.f);
    }
    __syncthreads();

    // ---- maxpool(2,2): [16][30] -> [16][15] ----
    if (tid < 240) {
        int co = tid / 15, j = tid - co * 15;
        sP[co * 15 + j] = fmaxf(s5[co * 30 + 2*j], s5[co * 30 + 2*j + 1]);
    }
    __syncthreads();

    // ---- conv6 (16 -> 32, k=5) + ReLU: [32][11] ----
    if (tid < 352) {
        int co = tid / 11, l = tid - co * 11;
        float acc = b6[co];
        for (int ci = 0; ci < 16; ++ci) {
            const float* wr = w6 + (co * 16 + ci) * 5;
            const float* pr = sP + ci * 15 + l;
            acc = fmaf(wr[0], pr[0], fmaf(wr[1], pr[1], fmaf(wr[2], pr[2],
                  fmaf(wr[3], pr[3], fmaf(wr[4], pr[4], acc)))));
        }
        s6[co * 11 + l] = fmaxf(acc, 0.f);
    }
    __syncthreads();

    // ---- fc1 (352 -> 128) + ReLU ----
    {
        int j = tid & 127, part = tid >> 7;  // 0..3
        int ibeg = part * 88, iend = ibeg + 88;
        float acc = (part == 0) ? fb1[j] : 0.f;
        for (int i = ibeg; i < iend; ++i)
            acc = fmaf(s6[i], fw1[i * 128 + j], acc);
        sFc[part * 128 + j] = acc;
    }
    __syncthreads();
    if (tid < 128) {
        float v = sFc[tid] + sFc[128 + tid] + sFc[256 + tid] + sFc[384 + tid];
        sO1[tid] = fmaxf(v, 0.f);
    }
    __syncthreads();

    // ---- fc2 (128 -> 10) + log_softmax ----
    if (tid < 10) {
        float acc = fb2[tid];
        for (int k = 0; k < 128; ++k)
            acc = fmaf(sO1[k], fw2[k * 10 + tid], acc);
        sZ[tid] = acc;
    }
    __syncthreads();
    if (tid < 10) {
        float m = sZ[0];
        for (int c = 1; c < 10; ++c) m = fmaxf(m, sZ[c]);
        float se = 0.f;
        for (int c = 0; c < 10; ++c) se += expf(sZ[c] - m);
        out[g * 10 + tid] = sZ[tid] - m - logf(se);
    }
}

extern "C" void kernel_launch(void* const* d_in, const int* in_sizes, int n_in,
                              void* d_out, int out_size, void* d_ws, size_t ws_size,
                              hipStream_t stream) {
    const float* x   = (const float*)d_in[0];
    const int*   ei  = (const int*)d_in[1];
    const int*   src = ei;
    const int*   dst = ei + N_EDGES_C;
    const float* W1 = (const float*)d_in[3];  const float* b1 = (const float*)d_in[4];
    const float* W2 = (const float*)d_in[5];  const float* b2 = (const float*)d_in[6];
    const float* W3 = (const float*)d_in[7];  const float* b3 = (const float*)d_in[8];
    const float* W4 = (const float*)d_in[9];  const float* b4 = (const float*)d_in[10];
    const float* w5 = (const float*)d_in[11]; const float* b5 = (const float*)d_in[12];
    const float* w6 = (const float*)d_in[13]; const float* b6 = (const float*)d_in[14];
    const float* fw1 = (const float*)d_in[15]; const float* fb1 = (const float*)d_in[16];
    const float* fw2 = (const float*)d_in[17]; const float* fb2 = (const float*)d_in[18];
    float* out = (float*)d_out;

    int* gcur = (int*)d_ws;
    unsigned short* slots = (unsigned short*)((char*)d_ws + 4096);

    hipMemsetAsync(gcur, 0, 4096, stream);

    bucket_kernel<<<(N_EDGES_C + 8191) / 8192, 1024, 0, stream>>>(src, dst, gcur, slots);

    size_t smem = (size_t)SMEM_FLOATS * sizeof(float);  // 54,000 B -> 3 blocks/CU
    hipFuncSetAttribute((const void*)dgcnn_kernel,
                        hipFuncAttributeMaxDynamicSharedMemorySize, (int)smem);
    dgcnn_kernel<<<N_GRAPHS_C, 512, smem, stream>>>(
        x, gcur, slots, W1, b1, W2, b2, W3, b3, W4, b4,
        w5, b5, w6, b6, fw1, fb1, fw2, fb2, out);
}

// Round 7
// 193.486 us; speedup vs baseline: 2.7670x; 1.0534x over previous
//
#include <hip/hip_runtime.h>

#define N_GRAPHS_C 1000
#define NPG_C      100
#define N_EDGES_C  3200000
#define KTOP_C     30
#define CAP        4096      // per-graph edge-slot capacity (mean 3200, sigma ~57)

__device__ __forceinline__ float ftanh(float x) {
    float e = __expf(2.0f * x);
    return 1.0f - 2.0f * __builtin_amdgcn_rcpf(e + 1.0f);
}

// ---------------- workspace layout (bytes) ----------------
// [0, 4096)            : gcur  int[1024]  (per-graph cursors; memset to 0)
// [4096, 4096+8.2MB)   : slots u16[1000*4096]  packed edges (d<<7 | s)

__global__ __launch_bounds__(1024)
void bucket_kernel(const int* __restrict__ src, const int* __restrict__ dst,
                   int* __restrict__ gcur, unsigned short* __restrict__ slots) {
    __shared__ int hist[N_GRAPHS_C];
    const int tid = threadIdx.x;
    const int base = blockIdx.x * 8192;
    for (int i = tid; i < N_GRAPHS_C; i += 1024) hist[i] = 0;
    __syncthreads();

    int g[8]; unsigned short pk[8]; bool v[8];
    #pragma unroll
    for (int k = 0; k < 8; ++k) {
        int e = base + tid + k * 1024;
        v[k] = false;
        if (e < N_EDGES_C) {
            int s = src[e], d = dst[e];
            if (s != d) {
                int gg = s / NPG_C;           // src and dst share the graph
                g[k] = gg;
                pk[k] = (unsigned short)(((d - gg * NPG_C) << 7) | (s - gg * NPG_C));
                v[k] = true;
                atomicAdd(&hist[gg], 1);
            }
        }
    }
    __syncthreads();
    for (int i = tid; i < N_GRAPHS_C; i += 1024) {
        int c = hist[i];
        hist[i] = atomicAdd(&gcur[i], c);     // reserve [base, base+c) globally
    }
    __syncthreads();
    #pragma unroll
    for (int k = 0; k < 8; ++k) {
        if (v[k]) {
            int pos = atomicAdd(&hist[g[k]], 1);
            if (pos < CAP) slots[g[k] * CAP + pos] = pk[k];
        }
    }
}

// ---------------- main per-graph kernel ----------------
// LDS (float offsets), total 6232 floats = 24,928 B -> 4 blocks/CU (32 waves):
//  cnt32 u32[2600] (= u8[100][104], rows padded to 104, pads stay 0) : [0, 2600)
//  buf   f32[3328]  Td^t[32][104] / x-rows[100][32] / pooled[30][100]: [2600, 5928)
//  dis   f32[100]                                                    : [5928, 6028)
//  t4    f32[104] (srank aliases later)                              : [6028, 6132)
//  sX4   f32[100]                                                    : [6132, 6232)
//  tail s5/sP/s6/sO1/sFc/sZ (1728 floats) alias the cnt region (dead after L4)
#define SMEM_FLOATS 6232

extern "C" __global__ __launch_bounds__(512, 8)
void dgcnn_kernel(const float* __restrict__ x,
                  const int* __restrict__ gcur, const unsigned short* __restrict__ slots,
                  const float* __restrict__ W1, const float* __restrict__ b1,
                  const float* __restrict__ W2, const float* __restrict__ b2,
                  const float* __restrict__ W3, const float* __restrict__ b3,
                  const float* __restrict__ W4, const float* __restrict__ b4,
                  const float* __restrict__ w5, const float* __restrict__ b5,
                  const float* __restrict__ w6, const float* __restrict__ b6,
                  const float* __restrict__ fw1, const float* __restrict__ fb1,
                  const float* __restrict__ fw2, const float* __restrict__ fb2,
                  float* __restrict__ out)
{
    extern __shared__ float sm[];
    unsigned*            cnt32 = (unsigned*)sm;              // 2600 words
    const unsigned char* cnt8  = (const unsigned char*)sm;   // u8[100][104]
    float* buf = sm + 2600;                // 3328
    float* dis = sm + 5928;                // 100
    float* t4  = sm + 6028;                // 104
    float* sX4 = sm + 6132;                // 100
    int*   srank  = (int*)t4;              // aliases t4 (dead after L4)
    float* pooled = buf;                   // [30][100] after GCN
    float* s5  = sm;                       // 480  (cnt dead after L4)
    float* sP  = sm + 480;                 // 240
    float* s6  = sm + 720;                 // 352
    float* sO1 = sm + 1072;                // 128
    float* sFc = sm + 1200;                // 512
    float* sZ  = sm + 1712;                // 16

    const int tid = threadIdx.x;
    const int g   = blockIdx.x;
    const int f   = tid & 31;
    const int i0  = tid >> 5;              // 0..15

    const float* xg = x + (size_t)g * NPG_C * 128;

    // ---- init: zero counts, Td pads, t4 ----
    for (int idx = tid; idx < 2600; idx += 512) cnt32[idx] = 0u;
    if (tid < 128) buf[(tid >> 2) * 104 + 100 + (tid & 3)] = 0.f;
    if (tid < 104) t4[tid] = 0.f;
    __syncthreads();

    // ---- scatter u8 counts (packed u32 atomics; row stride 104) ----
    {
        int ec = gcur[g]; if (ec > CAP) ec = CAP;
        for (int k = tid; k < ec; k += 512) {
            unsigned e = slots[g * CAP + k];
            unsigned idx = (e >> 7) * 104 + (e & 127);
            atomicAdd(&cnt32[idx >> 2], 1u << ((idx & 3) * 8));
        }
    }
    __syncthreads();

    // ---- dis = rsqrt(rowsum + 1) ----
    if (tid < 100) {
        const unsigned* rw = cnt32 + tid * 26;
        unsigned s = 0;
        #pragma unroll
        for (int k = 0; k < 26; ++k) {
            unsigned v = rw[k];
            s += (v & 0xffu) + ((v >> 8) & 0xffu) + ((v >> 16) & 0xffu) + (v >> 24);
        }
        dis[tid] = rsqrtf((float)s + 1.0f);
    }
    __syncthreads();

    float xr1[7], xr2[7], xr3[7], sc[7], tt[7];

    // ---- layer 1: T1 = X @ W1 (128 -> 32); store Td1^t[f][i] = T1[i][f]*dis[i] ----
    {
        float acc[7] = {0,0,0,0,0,0,0};
        for (int c4 = 0; c4 < 128; c4 += 4) {
            float w0 = W1[(c4+0)*32+f], w1 = W1[(c4+1)*32+f];
            float w2 = W1[(c4+2)*32+f], w3 = W1[(c4+3)*32+f];
            #pragma unroll
            for (int r = 0; r < 7; ++r) {
                int i = i0 + (r << 4);
                if (i < 100) {
                    const float4 xv = *(const float4*)&xg[i*128 + c4];
                    acc[r] = fmaf(xv.x,w0, fmaf(xv.y,w1, fmaf(xv.z,w2, fmaf(xv.w,w3, acc[r]))));
                }
            }
        }
        #pragma unroll
        for (int r = 0; r < 7; ++r) {
            int i = i0 + (r << 4);
            if (i < 100) { float v = acc[r] * dis[i]; sc[r] = v; buf[f*104 + i] = v; }
        }
    }
    __syncthreads();

    // ---- AGG: acc_i,f = sum_k cnt8[i][k] * Td[k][f]; out = tanh(dis_i*(acc+Td[i][f])+b) ----
    // pads k=100..103: cnt8 = 0 exactly -> contribute 0 (Td pad values finite).
#define AGG_REG(XR, BIAS)                                                           \
    {                                                                               \
        float acc[7] = {0,0,0,0,0,0,0};                                             \
        const float* tp = buf + f * 104;                                            \
        for (int kc = 0; kc < 13; ++kc) {                                           \
            const int k8 = kc << 3;                                                 \
            float4 ta = *(const float4*)&tp[k8];                                    \
            float4 tb = *(const float4*)&tp[k8 + 4];                                \
            _Pragma("unroll")                                                       \
            for (int r = 0; r < 7; ++r) {                                           \
                int i = i0 + (r << 4);                                              \
                if (i < 100) {                                                      \
                    uint2 cw = *(const uint2*)(cnt8 + i * 104 + k8);                \
                    acc[r] = fmaf((float)(cw.x & 255u),          ta.x,              \
                             fmaf((float)((cw.x >> 8) & 255u),   ta.y,              \
                             fmaf((float)((cw.x >> 16) & 255u),  ta.z,              \
                             fmaf((float)(cw.x >> 24),           ta.w,              \
                             fmaf((float)(cw.y & 255u),          tb.x,              \
                             fmaf((float)((cw.y >> 8) & 255u),   tb.y,              \
                             fmaf((float)((cw.y >> 16) & 255u),  tb.z,              \
                             fmaf((float)(cw.y >> 24),           tb.w,              \
                                  acc[r]))))))));                                   \
                }                                                                   \
            }                                                                       \
        }                                                                           \
        float bf_ = BIAS[f];                                                        \
        _Pragma("unroll")                                                           \
        for (int r = 0; r < 7; ++r) {                                               \
            int i = i0 + (r << 4);                                                  \
            if (i < 100) XR[r] = ftanh(dis[i] * (acc[r] + sc[r]) + bf_);            \
        }                                                                           \
    }

    // ---- store x rows (row-major) into buf ----
#define STORE_ROWS(XR)                                                              \
    {                                                                               \
        _Pragma("unroll")                                                           \
        for (int r = 0; r < 7; ++r) { int i = i0 + (r << 4); if (i < 100) buf[i*32 + f] = XR[r]; } \
    }

    // ---- XW: TT[r] = (buf_rows @ W)[i][f] ----
#define XW32(TT, W)                                                                 \
    {                                                                               \
        _Pragma("unroll")                                                           \
        for (int r = 0; r < 7; ++r) TT[r] = 0.f;                                    \
        for (int c4 = 0; c4 < 32; c4 += 4) {                                        \
            float w0 = W[(c4+0)*32+f], w1 = W[(c4+1)*32+f];                         \
            float w2 = W[(c4+2)*32+f], w3 = W[(c4+3)*32+f];                         \
            _Pragma("unroll")                                                       \
            for (int r = 0; r < 7; ++r) {                                           \
                int i = i0 + (r << 4);                                              \
                if (i < 100) {                                                      \
                    const float4 xv = *(const float4*)&buf[i*32 + c4];              \
                    TT[r] = fmaf(xv.x,w0, fmaf(xv.y,w1, fmaf(xv.z,w2, fmaf(xv.w,w3, TT[r])))); \
                }                                                                   \
            }                                                                       \
        }                                                                           \
    }

    // ---- store Td^t[f][i] = TT*dis_i; keep sc ----
#define STORE_TT(TT)                                                                \
    {                                                                               \
        _Pragma("unroll")                                                           \
        for (int r = 0; r < 7; ++r) {                                               \
            int i = i0 + (r << 4);                                                  \
            if (i < 100) { float v = TT[r] * dis[i]; sc[r] = v; buf[f*104 + i] = v; } \
        }                                                                           \
    }

    AGG_REG(xr1, b1);
    __syncthreads();
    STORE_ROWS(xr1);
    __syncthreads();
    XW32(tt, W2);
    __syncthreads();
    STORE_TT(tt);
    __syncthreads();
    AGG_REG(xr2, b2);
    __syncthreads();
    STORE_ROWS(xr2);
    __syncthreads();
    XW32(tt, W3);
    __syncthreads();
    STORE_TT(tt);
    __syncthreads();
    AGG_REG(xr3, b3);

    // ---- layer 4 (32 -> 1): t4d[i] = dis_i * (x3 row . W4) via shfl reduce ----
    {
        float w4f = W4[f];
        #pragma unroll
        for (int r = 0; r < 7; ++r) {
            int i = i0 + (r << 4);
            float v = (i < 100) ? xr3[r] * w4f : 0.f;
            #pragma unroll
            for (int off = 16; off >= 1; off >>= 1) v += __shfl_xor(v, off, 32);
            if (f == 0 && i < 100) t4[i] = v * dis[i];
        }
    }
    __syncthreads();
    if (tid < 100) {
        float acc = 0.f;
        const unsigned char* cr = cnt8 + tid * 104;
        for (int kc = 0; kc < 13; ++kc) {
            const int k8 = kc << 3;
            uint2 cw = *(const uint2*)(cr + k8);
            float4 ta = *(const float4*)&t4[k8];
            float4 tb = *(const float4*)&t4[k8 + 4];
            acc = fmaf((float)(cw.x & 255u),          ta.x,
                  fmaf((float)((cw.x >> 8) & 255u),   ta.y,
                  fmaf((float)((cw.x >> 16) & 255u),  ta.z,
                  fmaf((float)(cw.x >> 24),           ta.w,
                  fmaf((float)(cw.y & 255u),          tb.x,
                  fmaf((float)((cw.y >> 8) & 255u),   tb.y,
                  fmaf((float)((cw.y >> 16) & 255u),  tb.z,
                  fmaf((float)(cw.y >> 24),           tb.w, acc))))))));
        }
        sX4[tid] = tanhf(dis[tid] * (acc + t4[tid]) + b4[0]);  // exact tanh: sort keys
    }
    __syncthreads();

    // ---- SortAggregation: stable rank (value desc, index asc), top-30 ----
    if (tid < 100) {
        float vi = sX4[tid];
        int r = 0;
        for (int j = 0; j < 100; ++j) {
            float vj = sX4[j];
            r += (vj > vi) || (vj == vi && j < tid);
        }
        srank[tid] = r;        // overwrites dead t4
    }
    __syncthreads();

    // ---- gather top-30 rows into pooled[30][100] (aliases buf) ----
    #pragma unroll
    for (int r = 0; r < 7; ++r) {
        int i = i0 + (r << 4);
        if (i < 100) {
            int rk = srank[i];
            if (rk < KTOP_C) {
                float* pr = pooled + rk * 100;
                pr[f]      = xr1[r];
                pr[32 + f] = xr2[r];
                pr[64 + f] = xr3[r];
                if (f == 0) pr[96] = sX4[i];
            }
        }
    }
    __syncthreads();

    // ---- conv5 (97 -> 16) + ReLU ----
    if (tid < 480) {
        int l = tid >> 4, co = tid & 15;
        const float* pr = pooled + l * 100;
        const float* wr = w5 + co * 97;
        float acc = b5[co];
        for (int c4 = 0; c4 < 96; c4 += 4) {
            const float4 pv = *(const float4*)&pr[c4];
            acc = fmaf(pv.x, wr[c4+0], fmaf(pv.y, wr[c4+1], fmaf(pv.z, wr[c4+2], fmaf(pv.w, wr[c4+3], acc))));
        }
        acc = fmaf(pr[96], wr[96], acc);
        s5[co * 30 + l] = fmaxf(acc, 0.f);
    }
    __syncthreads();

    // ---- maxpool(2,2): [16][30] -> [16][15] ----
    if (tid < 240) {
        int co = tid / 15, j = tid - co * 15;
        sP[co * 15 + j] = fmaxf(s5[co * 30 + 2*j], s5[co * 30 + 2*j + 1]);
    }
    __syncthreads();

    // ---- conv6 (16 -> 32, k=5) + ReLU: [32][11] ----
    if (tid < 352) {
        int co = tid / 11, l = tid - co * 11;
        float acc = b6[co];
        for (int ci = 0; ci < 16; ++ci) {
            const float* wr = w6 + (co * 16 + ci) * 5;
            const float* pr = sP + ci * 15 + l;
            acc = fmaf(wr[0], pr[0], fmaf(wr[1], pr[1], fmaf(wr[2], pr[2],
                  fmaf(wr[3], pr[3], fmaf(wr[4], pr[4], acc)))));
        }
        s6[co * 11 + l] = fmaxf(acc, 0.f);
    }
    __syncthreads();

    // ---- fc1 (352 -> 128) + ReLU ----
    {
        int j = tid & 127, part = tid >> 7;  // 0..3
        int ibeg = part * 88, iend = ibeg + 88;
        float acc = (part == 0) ? fb1[j] : 0.f;
        for (int i = ibeg; i < iend; ++i)
            acc = fmaf(s6[i], fw1[i * 128 + j], acc);
        sFc[part * 128 + j] = acc;
    }
    __syncthreads();
    if (tid < 128) {
        float v = sFc[tid] + sFc[128 + tid] + sFc[256 + tid] + sFc[384 + tid];
        sO1[tid] = fmaxf(v, 0.f);
    }
    __syncthreads();

    // ---- fc2 (128 -> 10) + log_softmax ----
    if (tid < 10) {
        float acc = fb2[tid];
        for (int k = 0; k < 128; ++k)
            acc = fmaf(sO1[k], fw2[k * 10 + tid], acc);
        sZ[tid] = acc;
    }
    __syncthreads();
    if (tid < 10) {
        float m = sZ[0];
        for (int c = 1; c < 10; ++c) m = fmaxf(m, sZ[c]);
        float se = 0.f;
        for (int c = 0; c < 10; ++c) se += expf(sZ[c] - m);
        out[g * 10 + tid] = sZ[tid] - m - logf(se);
    }
}

extern "C" void kernel_launch(void* const* d_in, const int* in_sizes, int n_in,
                              void* d_out, int out_size, void* d_ws, size_t ws_size,
                              hipStream_t stream) {
    const float* x   = (const float*)d_in[0];
    const int*   ei  = (const int*)d_in[1];
    const int*   src = ei;
    const int*   dst = ei + N_EDGES_C;
    const float* W1 = (const float*)d_in[3];  const float* b1 = (const float*)d_in[4];
    const float* W2 = (const float*)d_in[5];  const float* b2 = (const float*)d_in[6];
    const float* W3 = (const float*)d_in[7];  const float* b3 = (const float*)d_in[8];
    const float* W4 = (const float*)d_in[9];  const float* b4 = (const float*)d_in[10];
    const float* w5 = (const float*)d_in[11]; const float* b5 = (const float*)d_in[12];
    const float* w6 = (const float*)d_in[13]; const float* b6 = (const float*)d_in[14];
    const float* fw1 = (const float*)d_in[15]; const float* fb1 = (const float*)d_in[16];
    const float* fw2 = (const float*)d_in[17]; const float* fb2 = (const float*)d_in[18];
    float* out = (float*)d_out;

    int* gcur = (int*)d_ws;
    unsigned short* slots = (unsigned short*)((char*)d_ws + 4096);

    hipMemsetAsync(gcur, 0, 4096, stream);

    bucket_kernel<<<(N_EDGES_C + 8191) / 8192, 1024, 0, stream>>>(src, dst, gcur, slots);

    size_t smem = (size_t)SMEM_FLOATS * sizeof(float);  // 24,928 B -> 4 blocks/CU
    hipFuncSetAttribute((const void*)dgcnn_kernel,
                        hipFuncAttributeMaxDynamicSharedMemorySize, (int)smem);
    dgcnn_kernel<<<N_GRAPHS_C, 512, smem, stream>>>(
        x, gcur, slots, W1, b1, W2, b2, W3, b3, W4, b4,
        w5, b5, w6, b6, fw1, fb1, fw2, fb2, out);
}